// Round 12
// baseline (4584.394 us; speedup 1.0000x reference)
//
#include <hip/hip_runtime.h>
#include <hip/hip_cooperative_groups.h>

namespace cg = cooperative_groups;

#define N 8192
#define DK 256
#define LOG2E 1.4426950408889634f
#define LN2   0.6931471805599453f
#define ZS    2.5f            // int8 dequant scale (Zl = q * ZS)
#define QS    1.1541560327f   // 2*log2e / ZS  (fp32 acc -> q units)
#define BIAS  320.0f          // 128 * ZS ; duals stored shifted by -BIAS
// log2(8192) = 13 exactly; (loga+logb) in log2 units = -26

typedef unsigned short u16;
typedef u16   ushort8 __attribute__((ext_vector_type(8)));
typedef __bf16 bf16x8 __attribute__((ext_vector_type(8)));
typedef float  f32x4  __attribute__((ext_vector_type(4)));

__device__ __forceinline__ u16 f2bf(float f){
  unsigned u = __builtin_bit_cast(unsigned, f);
  return (u16)((u + 0x7fffu + ((u >> 16) & 1u)) >> 16);   // RNE fp32->bf16
}
__device__ __forceinline__ float ex2(float x){            // v_exp_f32 = 2^x
  float r; asm("v_exp_f32 %0, %1" : "=v"(r) : "v"(x)); return r;
}
__device__ __forceinline__ float lg2(float x){            // v_log_f32 = log2(x)
  float r; asm("v_log_f32 %0, %1" : "=v"(r) : "v"(x)); return r;
}
__device__ __forceinline__ float cub0(unsigned u){ float r; asm("v_cvt_f32_ubyte0 %0, %1":"=v"(r):"v"(u)); return r; }
__device__ __forceinline__ float cub1(unsigned u){ float r; asm("v_cvt_f32_ubyte1 %0, %1":"=v"(r):"v"(u)); return r; }
__device__ __forceinline__ float cub2(unsigned u){ float r; asm("v_cvt_f32_ubyte2 %0, %1":"=v"(r):"v"(u)); return r; }
__device__ __forceinline__ float cub3(unsigned u){ float r; asm("v_cvt_f32_ubyte3 %0, %1":"=v"(r):"v"(u)); return r; }

// premax: sum of 4 exp2 terms, t_e = q_e*ZS + (g_e - M)
__device__ __forceinline__ float quad(unsigned u, float4 gv, float M){
  float t0 = __builtin_fmaf(cub0(u), ZS, gv.x - M);
  float t1 = __builtin_fmaf(cub1(u), ZS, gv.y - M);
  float t2 = __builtin_fmaf(cub2(u), ZS, gv.z - M);
  float t3 = __builtin_fmaf(cub3(u), ZS, gv.w - M);
  return (ex2(t0) + ex2(t1)) + (ex2(t2) + ex2(t3));
}
__device__ __forceinline__ float pm16(const uint4 a, const float* gp, float M){
  const float4 g0 = *(const float4*)(gp);
  const float4 g1 = *(const float4*)(gp + 4);
  const float4 g2 = *(const float4*)(gp + 8);
  const float4 g3 = *(const float4*)(gp + 12);
  return (quad(a.x, g0, M) + quad(a.y, g1, M))
       + (quad(a.z, g2, M) + quad(a.w, g3, M));
}
// online-max: process 16 elems of one row
__device__ __forceinline__ void upd16(const uint4 a, const float* gp, float& m, float& s){
  const float4 g0 = *(const float4*)(gp);
  const float4 g1 = *(const float4*)(gp + 4);
  const float4 g2 = *(const float4*)(gp + 8);
  const float4 g3 = *(const float4*)(gp + 12);
  float t0  = __builtin_fmaf(cub0(a.x), ZS, g0.x);
  float t1  = __builtin_fmaf(cub1(a.x), ZS, g0.y);
  float t2  = __builtin_fmaf(cub2(a.x), ZS, g0.z);
  float t3  = __builtin_fmaf(cub3(a.x), ZS, g0.w);
  float t4  = __builtin_fmaf(cub0(a.y), ZS, g1.x);
  float t5  = __builtin_fmaf(cub1(a.y), ZS, g1.y);
  float t6  = __builtin_fmaf(cub2(a.y), ZS, g1.z);
  float t7  = __builtin_fmaf(cub3(a.y), ZS, g1.w);
  float t8  = __builtin_fmaf(cub0(a.z), ZS, g2.x);
  float t9  = __builtin_fmaf(cub1(a.z), ZS, g2.y);
  float t10 = __builtin_fmaf(cub2(a.z), ZS, g2.z);
  float t11 = __builtin_fmaf(cub3(a.z), ZS, g2.w);
  float t12 = __builtin_fmaf(cub0(a.w), ZS, g3.x);
  float t13 = __builtin_fmaf(cub1(a.w), ZS, g3.y);
  float t14 = __builtin_fmaf(cub2(a.w), ZS, g3.z);
  float t15 = __builtin_fmaf(cub3(a.w), ZS, g3.w);
  float a0 = fmaxf(t0, t1),   a1 = fmaxf(t2, t3);
  float a2 = fmaxf(t4, t5),   a3 = fmaxf(t6, t7);
  float a4 = fmaxf(t8, t9),   a5 = fmaxf(t10, t11);
  float a6 = fmaxf(t12, t13), a7 = fmaxf(t14, t15);
  float b0 = fmaxf(a0, a1), b1 = fmaxf(a2, a3), b2 = fmaxf(a4, a5), b3 = fmaxf(a6, a7);
  float nm = fmaxf(fmaxf(fmaxf(b0, b1), fmaxf(b2, b3)), m);
  float s0 = ex2(t0 - nm) + ex2(t1 - nm) + ex2(t2 - nm) + ex2(t3 - nm)
           + ex2(t4 - nm) + ex2(t5 - nm) + ex2(t6 - nm) + ex2(t7 - nm);
  float s1 = ex2(t8 - nm) + ex2(t9 - nm) + ex2(t10 - nm) + ex2(t11 - nm)
           + ex2(t12 - nm) + ex2(t13 - nm) + ex2(t14 - nm) + ex2(t15 - nm);
  s = __builtin_fmaf(s, ex2(m - nm), s0 + s1);
  m = nm;
}

// ---------------------------------------------------------------------------
// prep: row sum-of-squares + bf16 copies + init gts = -y2*LOG2E - BIAS (g0=0)
// ---------------------------------------------------------------------------
__global__ __launch_bounds__(256) void prep_k(const float* __restrict__ x, const float* __restrict__ y,
                                              u16* __restrict__ xb, u16* __restrict__ yb,
                                              float* __restrict__ x2, float* __restrict__ y2,
                                              float* __restrict__ gts){
  const int w = threadIdx.x >> 6, l = threadIdx.x & 63;
  const int r = blockIdx.x * 4 + w;         // 0..16383
  const bool isx = r < N;
  const int rr = isx ? r : r - N;
  const float* src = (isx ? x : y) + (size_t)rr * DK;
  float4 v = *(const float4*)(src + l * 4);
  ushort4 bv;
  bv.x = f2bf(v.x); bv.y = f2bf(v.y); bv.z = f2bf(v.z); bv.w = f2bf(v.w);
  *(ushort4*)((isx ? xb : yb) + (size_t)rr * DK + l * 4) = bv;
  float p = v.x*v.x + v.y*v.y + v.z*v.z + v.w*v.w;
  #pragma unroll
  for (int off = 32; off > 0; off >>= 1) p += __shfl_down(p, off);
  if (l == 0){
    if (isx) x2[rr] = p;
    else { y2[rr] = p; gts[rr] = -p * LOG2E - BIAS; }
  }
}

// ---------------------------------------------------------------------------
// gemm: z = xb*yb^T (bf16 MFMA). Quantize Zl = 2*log2e*z to biased uint8,
// stage tiles in LDS, store zq and zqT coalesced dwordx4.
// ---------------------------------------------------------------------------
__global__ __launch_bounds__(256) void gemm_k(const u16* __restrict__ xb, const u16* __restrict__ yb,
                                              unsigned char* __restrict__ zq,
                                              unsigned char* __restrict__ zqT){
  __shared__ __align__(16) u16 As[128 * 72];
  __shared__ __align__(16) u16 Bs[128 * 72];
  const int t = threadIdx.x;
  const int w = t >> 6, l = t & 63;
  const int wm = w >> 1, wn = w & 1;
  const int brow = blockIdx.y * 128, bcol = blockIdx.x * 128;
  const int tr = t >> 3, tc = t & 7;
  f32x4 acc[4][4] = {};
  for (int ks = 0; ks < 4; ++ks){
    #pragma unroll
    for (int rr = 0; rr < 4; ++rr){
      const int row = tr + rr * 32;
      *(ushort8*)&As[row * 72 + tc * 8] = *(const ushort8*)&xb[(size_t)(brow + row) * DK + ks * 64 + tc * 8];
      *(ushort8*)&Bs[row * 72 + tc * 8] = *(const ushort8*)&yb[(size_t)(bcol + row) * DK + ks * 64 + tc * 8];
    }
    __syncthreads();
    #pragma unroll
    for (int kk = 0; kk < 2; ++kk){
      bf16x8 av[4], bv[4];
      #pragma unroll
      for (int mi = 0; mi < 4; ++mi){
        const int ar = wm * 64 + mi * 16 + (l & 15);
        av[mi] = __builtin_bit_cast(bf16x8, *(const ushort8*)&As[ar * 72 + kk * 32 + (l >> 4) * 8]);
      }
      #pragma unroll
      for (int ni = 0; ni < 4; ++ni){
        const int br = wn * 64 + ni * 16 + (l & 15);
        bv[ni] = __builtin_bit_cast(bf16x8, *(const ushort8*)&Bs[br * 72 + kk * 32 + (l >> 4) * 8]);
      }
      #pragma unroll
      for (int mi = 0; mi < 4; ++mi)
        #pragma unroll
        for (int ni = 0; ni < 4; ++ni)
          acc[mi][ni] = __builtin_amdgcn_mfma_f32_16x16x32_bf16(av[mi], bv[ni], acc[mi][ni], 0, 0, 0);
    }
    __syncthreads();
  }
  // quantize: Cs row-major [128][128]; Ct col-major [col][row] stride 144
  unsigned char* Cs = (unsigned char*)As;
  unsigned char* Ct = (unsigned char*)Bs;
  #pragma unroll
  for (int mi = 0; mi < 4; ++mi){
    const int rowb = wm * 64 + mi * 16 + (l >> 4) * 4;
    #pragma unroll
    for (int ni = 0; ni < 4; ++ni){
      const int col = wn * 64 + ni * 16 + (l & 15);
      unsigned pk = 0;
      #pragma unroll
      for (int rr = 0; rr < 4; ++rr){
        float q = fminf(fmaxf(acc[mi][ni][rr] * QS, -127.f), 127.f);
        unsigned b = (unsigned)((int)__builtin_rintf(q) + 128) & 255u;
        Cs[(rowb + rr) * 128 + col] = (unsigned char)b;
        pk |= b << (8 * rr);
      }
      *(unsigned*)(Ct + col * 144 + rowb) = pk;
    }
  }
  __syncthreads();
  const int trow0 = t >> 3, kseg = t & 7;
  #pragma unroll
  for (int ii = 0; ii < 4; ++ii){
    const int row = trow0 + ii * 32;
    int4 v = *(const int4*)(Cs + row * 128 + kseg * 16);
    *(int4*)(zq + (size_t)(brow + row) * N + bcol + kseg * 16) = v;
    int4 vt = *(const int4*)(Ct + row * 144 + kseg * 16);
    *(int4*)(zqT + (size_t)(bcol + row) * N + brow + kseg * 16) = vt;
  }
}

// ---------------------------------------------------------------------------
// shared per-row-pair sweep bodies (rows r0, r0+1; duals staged in gl)
// PHASE 0: online max (bootstrap) — seeds pmax.  PHASE 1: premax.
// ---------------------------------------------------------------------------
template<int PHASE>
__device__ __forceinline__ void do_pair(const unsigned char* __restrict__ z,
                                        const float* gl, int r0, int l,
                                        float* __restrict__ dout,
                                        float* __restrict__ pmax){
  const unsigned char* zr = z + (size_t)r0 * N + l * 16;
  float lse0, lse1;
  if (PHASE == 0){
    float m0 = -1e30f, s0 = 0.f, m1 = -1e30f, s1 = 0.f;
    #pragma unroll 2
    for (int it = 0; it < 8; ++it){
      const uint4 a = *(const uint4*)(zr + it * 1024);
      const uint4 b = *(const uint4*)(zr + N + it * 1024);
      const float* gp = gl + it * 1024 + l * 16;
      upd16(a, gp, m0, s0);
      upd16(b, gp, m1, s1);
    }
    #pragma unroll
    for (int off = 32; off > 0; off >>= 1){
      float om = __shfl_down(m0, off), os = __shfl_down(s0, off);
      float nm = fmaxf(m0, om);
      s0 = __builtin_fmaf(s0, ex2(m0 - nm), os * ex2(om - nm)); m0 = nm;
      om = __shfl_down(m1, off); os = __shfl_down(s1, off);
      nm = fmaxf(m1, om);
      s1 = __builtin_fmaf(s1, ex2(m1 - nm), os * ex2(om - nm)); m1 = nm;
    }
    lse0 = m0 + lg2(s0); lse1 = m1 + lg2(s1);
  } else {
    const float M0 = pmax[r0], M1 = pmax[r0 + 1];
    float s0 = 0.f, s1 = 0.f;
    #pragma unroll 2
    for (int it = 0; it < 8; ++it){
      const uint4 a = *(const uint4*)(zr + it * 1024);
      const uint4 b = *(const uint4*)(zr + N + it * 1024);
      const float* gp = gl + it * 1024 + l * 16;
      s0 += pm16(a, gp, M0);
      s1 += pm16(b, gp, M1);
    }
    #pragma unroll
    for (int off = 32; off > 0; off >>= 1){
      s0 += __shfl_down(s0, off);
      s1 += __shfl_down(s1, off);
    }
    lse0 = M0 + lg2(s0); lse1 = M1 + lg2(s1);
  }
  if (l == 0){
    dout[r0]     = 13.0f - lse0 - BIAS;
    dout[r0 + 1] = 13.0f - lse1 - BIAS;
    pmax[r0]     = lse0;
    pmax[r0 + 1] = lse1;
  }
}

__device__ __forceinline__ void val_pair(const unsigned char* __restrict__ zq,
                                         const float* gl, int r0, int l,
                                         const float* __restrict__ pmaxF,
                                         const float* __restrict__ fts,
                                         const float* __restrict__ x2,
                                         float* __restrict__ contrib){
  const unsigned char* zr = zq + (size_t)r0 * N + l * 16;
  const float M0 = pmaxF[r0], M1 = pmaxF[r0 + 1];
  float s0 = 0.f, s1 = 0.f;
  #pragma unroll 2
  for (int it = 0; it < 8; ++it){
    const uint4 a = *(const uint4*)(zr + it * 1024);
    const uint4 b = *(const uint4*)(zr + N + it * 1024);
    const float* gp = gl + it * 1024 + l * 16;
    s0 += pm16(a, gp, M0);
    s1 += pm16(b, gp, M1);
  }
  #pragma unroll
  for (int off = 32; off > 0; off >>= 1){
    s0 += __shfl_down(s0, off);
    s1 += __shfl_down(s1, off);
  }
  if (l == 0){
    const float lse0 = M0 + lg2(s0), lse1 = M1 + lg2(s1);
    const float f0 = fts[r0] + BIAS, f1 = fts[r0 + 1] + BIAS;   // true FtL
    contrib[r0]     = (f0 * LN2 + x2[r0])     * ex2(f0 + lse0 - 26.0f);
    contrib[r0 + 1] = (f1 * LN2 + x2[r0 + 1]) * ex2(f1 + lse1 - 26.0f);
  }
}

// ---------------------------------------------------------------------------
// sink: ALL 100 half-iterations + value pass + reduction, one cooperative
// kernel. Grid 256 x 512 (1 block/CU guaranteed-feasible: 8 waves, 32KB LDS).
// Block owns 32 rows: 8 waves x 2 row-pairs (base, base+16).
// ---------------------------------------------------------------------------
__global__ __launch_bounds__(512, 2) void sink_k(
    const unsigned char* __restrict__ zq, const unsigned char* __restrict__ zqT,
    float* __restrict__ fts, float* __restrict__ gts,
    float* __restrict__ pmaxF, float* __restrict__ pmaxG,
    const float* __restrict__ x2, const float* __restrict__ y2,
    float* __restrict__ contrib, float* __restrict__ out){
  cg::grid_group grid = cg::this_grid();
  __shared__ __align__(16) float gl[8192];
  const int t = threadIdx.x;
  const int w = t >> 6, l = t & 63;
  const int rA = blockIdx.x * 32 + w * 2;
  const int rB = rA + 16;
  for (int s = 0; s < 100; ++s){
    const bool fs = !(s & 1);
    const unsigned char* z = fs ? zq : zqT;
    const float* din = fs ? gts : fts;
    float* dout = fs ? fts : gts;
    float* pmax = fs ? pmaxF : pmaxG;
    #pragma unroll
    for (int i = 0; i < 4; ++i){
      const int idx = (t + i * 512) * 4;
      *(float4*)(gl + idx) = *(const float4*)(din + idx);
    }
    __syncthreads();
    if (s < 4){
      do_pair<0>(z, gl, rA, l, dout, pmax);
      do_pair<0>(z, gl, rB, l, dout, pmax);
    } else {
      do_pair<1>(z, gl, rA, l, dout, pmax);
      do_pair<1>(z, gl, rB, l, dout, pmax);
    }
    grid.sync();   // full barrier: dual writes visible; gl safe to overwrite
  }
  // final value pass (f-side, duals = gts)
  #pragma unroll
  for (int i = 0; i < 4; ++i){
    const int idx = (t + i * 512) * 4;
    *(float4*)(gl + idx) = *(const float4*)(gts + idx);
  }
  __syncthreads();
  val_pair(zq, gl, rA, l, pmaxF, fts, x2, contrib);
  val_pair(zq, gl, rB, l, pmaxF, fts, x2, contrib);
  grid.sync();
  // final reduction on block 0
  if (blockIdx.x == 0){
    float a = 0.f, b = 0.f;
    for (int j = t; j < N; j += 512){
      a += contrib[j];
      b += (gts[j] + BIAS) * LN2 + y2[j];
    }
    gl[t] = a; gl[512 + t] = b;
    __syncthreads();
    for (int st = 256; st > 0; st >>= 1){
      if (t < st){ gl[t] += gl[t + st]; gl[512 + t] += gl[512 + t + st]; }
      __syncthreads();
    }
    if (t == 0) out[0] = sqrtf(gl[0] + gl[512] * (1.0f / (float)N));
  }
}

// ---------------------------------------------------------------------------
// FALLBACK PATH (round-10 kernels, proven): used if cooperative launch fails.
// ---------------------------------------------------------------------------
__global__ __launch_bounds__(256) void sweept_k(const unsigned char* __restrict__ z,
                                                const float* __restrict__ din,
                                                float* __restrict__ dout,
                                                float* __restrict__ pmax_out){
  const int w = threadIdx.x >> 6, l = threadIdx.x & 63;
  const int i = blockIdx.x * 4 + w;
  const unsigned char* zr = z + (size_t)i * N + l * 16;
  float m = -1e30f, s = 0.f;
  #pragma unroll 2
  for (int it = 0; it < 8; ++it){
    const uint4 zA = *(const uint4*)(zr + it * 1024);
    upd16(zA, din + it * 1024 + l * 16, m, s);
  }
  #pragma unroll
  for (int off = 32; off > 0; off >>= 1){
    float om = __shfl_down(m, off);
    float os = __shfl_down(s, off);
    float nm = fmaxf(m, om);
    s = __builtin_fmaf(s, ex2(m - nm), os * ex2(om - nm));
    m = nm;
  }
  if (l == 0){
    float lse2 = m + lg2(s);
    dout[i] = 13.0f - lse2 - BIAS;
    pmax_out[i] = lse2;
  }
}

template<int MODE>
__global__ __launch_bounds__(256) void sweepn_k(const unsigned char* __restrict__ z,
                                                const float* __restrict__ din,
                                                float* __restrict__ dout,
                                                const float* __restrict__ pmax_in,
                                                float* __restrict__ pmax_out,
                                                const float* __restrict__ fprev,
                                                const float* __restrict__ x2,
                                                float* __restrict__ contrib){
  __shared__ __align__(16) float gl[8192];
  const int t = threadIdx.x;
  #pragma unroll
  for (int i = 0; i < 8; ++i){
    const int idx = (t + i * 256) * 4;
    *(float4*)(gl + idx) = *(const float4*)(din + idx);
  }
  __syncthreads();
  const int w = t >> 6, l = t & 63;
  const int r0 = blockIdx.x * 8 + w * 2;
  const unsigned char* zr = z + (size_t)r0 * N + l * 16;
  const float M0 = pmax_in[r0], M1 = pmax_in[r0 + 1];
  float s0 = 0.f, s1 = 0.f;
  #pragma unroll 2
  for (int it = 0; it < 8; ++it){
    const uint4 a = *(const uint4*)(zr + it * 1024);
    const uint4 b = *(const uint4*)(zr + N + it * 1024);
    const float* gp = gl + it * 1024 + l * 16;
    s0 += pm16(a, gp, M0);
    s1 += pm16(b, gp, M1);
  }
  #pragma unroll
  for (int off = 32; off > 0; off >>= 1){
    s0 += __shfl_down(s0, off);
    s1 += __shfl_down(s1, off);
  }
  if (l == 0){
    const float lse0 = M0 + lg2(s0);
    const float lse1 = M1 + lg2(s1);
    if (MODE == 0){
      dout[r0]     = 13.0f - lse0 - BIAS;
      dout[r0 + 1] = 13.0f - lse1 - BIAS;
      pmax_out[r0]     = lse0;
      pmax_out[r0 + 1] = lse1;
    } else {
      const float f0 = fprev[r0] + BIAS;
      const float f1 = fprev[r0 + 1] + BIAS;
      contrib[r0]     = (f0 * LN2 + x2[r0])     * ex2(f0 + lse0 - 26.0f);
      contrib[r0 + 1] = (f1 * LN2 + x2[r0 + 1]) * ex2(f1 + lse1 - 26.0f);
    }
  }
}

__global__ __launch_bounds__(256) void finish_k(const float* __restrict__ contrib,
                                                const float* __restrict__ gts,
                                                const float* __restrict__ y2,
                                                float* __restrict__ out){
  __shared__ float s1[256], s2[256];
  const int t = threadIdx.x;
  float a = 0.f, b = 0.f;
  for (int j = t; j < N; j += 256){ a += contrib[j]; b += (gts[j] + BIAS) * LN2 + y2[j]; }
  s1[t] = a; s2[t] = b; __syncthreads();
  for (int st = 128; st > 0; st >>= 1){
    if (t < st){ s1[t] += s1[t + st]; s2[t] += s2[t + st]; }
    __syncthreads();
  }
  if (t == 0) out[0] = sqrtf(s1[0] + s2[0] * (1.0f / (float)N));
}

// ---------------------------------------------------------------------------
extern "C" void kernel_launch(void* const* d_in, const int* in_sizes, int n_in,
                              void* d_out, int out_size, void* d_ws, size_t ws_size,
                              hipStream_t stream){
  const float* x = (const float*)d_in[0];
  const float* y = (const float*)d_in[1];
  float* out = (float*)d_out;
  char* ws = (char*)d_ws;

  // workspace layout (bytes)
  unsigned char* zq  = (unsigned char*)(ws);              // 64 MiB
  unsigned char* zqT = (unsigned char*)(ws + 67108864);   // 64 MiB
  u16*   xb      = (u16*)  (ws + 134217728);              // 4 MiB
  u16*   yb      = (u16*)  (ws + 138412032);              // 4 MiB
  float* x2      = (float*)(ws + 142606336);
  float* y2      = (float*)(ws + 142639104);
  float* fts     = (float*)(ws + 142671872);
  float* gts     = (float*)(ws + 142704640);
  float* contrib = (float*)(ws + 142737408);
  float* pmaxF   = (float*)(ws + 142770176);
  float* pmaxG   = (float*)(ws + 142802944);

  prep_k<<<4096, 256, 0, stream>>>(x, y, xb, yb, x2, y2, gts);
  gemm_k<<<dim3(64, 64), 256, 0, stream>>>(xb, yb, zq, zqT);

  void* args[] = { (void*)&zq, (void*)&zqT, (void*)&fts, (void*)&gts,
                   (void*)&pmaxF, (void*)&pmaxG, (void*)&x2, (void*)&y2,
                   (void*)&contrib, (void*)&out };
  hipError_t err = hipLaunchCooperativeKernel((const void*)sink_k,
                                              dim3(256), dim3(512),
                                              args, 0, stream);
  if (err != hipSuccess){
    // deterministic fallback: identical math via the round-10 launch chain
    for (int it = 0; it < 2; ++it){
      sweept_k<<<2048, 256, 0, stream>>>(zq,  gts, fts, pmaxF);
      sweept_k<<<2048, 256, 0, stream>>>(zqT, fts, gts, pmaxG);
    }
    for (int s = 4; s < 100; ++s){
      if ((s & 1) == 0)
        sweepn_k<0><<<1024, 256, 0, stream>>>(zq,  gts, fts, pmaxF, pmaxF,
                                              nullptr, nullptr, nullptr);
      else
        sweepn_k<0><<<1024, 256, 0, stream>>>(zqT, fts, gts, pmaxG, pmaxG,
                                              nullptr, nullptr, nullptr);
    }
    sweepn_k<1><<<1024, 256, 0, stream>>>(zq, gts, nullptr, pmaxF, nullptr,
                                          fts, x2, contrib);
    finish_k<<<1, 256, 0, stream>>>(contrib, gts, y2, out);
  }
}

// Round 13
// 1827.170 us; speedup vs baseline: 2.5090x; 2.5090x over previous
//
#include <hip/hip_runtime.h>

#define N 8192
#define DK 256
#define LOG2E 1.4426950408889634f
#define LN2   0.6931471805599453f
#define ZS    2.5f            // int8 dequant scale (Zl = q * ZS)
#define QS    1.1541560327f   // 2*log2e / ZS  (fp32 acc -> q units)
#define BIAS  320.0f          // 128 * ZS ; duals stored shifted by -BIAS
// log2(8192) = 13 exactly; (loga+logb) in log2 units = -26

typedef unsigned short u16;
typedef u16   ushort8 __attribute__((ext_vector_type(8)));
typedef __bf16 bf16x8 __attribute__((ext_vector_type(8)));
typedef float  f32x4  __attribute__((ext_vector_type(4)));

__device__ __forceinline__ u16 f2bf(float f){
  unsigned u = __builtin_bit_cast(unsigned, f);
  return (u16)((u + 0x7fffu + ((u >> 16) & 1u)) >> 16);   // RNE fp32->bf16
}
__device__ __forceinline__ float ex2(float x){            // v_exp_f32 = 2^x
  float r; asm("v_exp_f32 %0, %1" : "=v"(r) : "v"(x)); return r;
}
__device__ __forceinline__ float lg2(float x){            // v_log_f32 = log2(x)
  float r; asm("v_log_f32 %0, %1" : "=v"(r) : "v"(x)); return r;
}
__device__ __forceinline__ float cub0(unsigned u){ float r; asm("v_cvt_f32_ubyte0 %0, %1":"=v"(r):"v"(u)); return r; }
__device__ __forceinline__ float cub1(unsigned u){ float r; asm("v_cvt_f32_ubyte1 %0, %1":"=v"(r):"v"(u)); return r; }
__device__ __forceinline__ float cub2(unsigned u){ float r; asm("v_cvt_f32_ubyte2 %0, %1":"=v"(r):"v"(u)); return r; }
__device__ __forceinline__ float cub3(unsigned u){ float r; asm("v_cvt_f32_ubyte3 %0, %1":"=v"(r):"v"(u)); return r; }

// premax: sum of 4 exp2 terms, t_e = q_e*ZS + (g_e - M)
__device__ __forceinline__ float quad(unsigned u, float4 gv, float M){
  float t0 = __builtin_fmaf(cub0(u), ZS, gv.x - M);
  float t1 = __builtin_fmaf(cub1(u), ZS, gv.y - M);
  float t2 = __builtin_fmaf(cub2(u), ZS, gv.z - M);
  float t3 = __builtin_fmaf(cub3(u), ZS, gv.w - M);
  return (ex2(t0) + ex2(t1)) + (ex2(t2) + ex2(t3));
}
// online-max: process 16 elems of one row
__device__ __forceinline__ void upd16(const uint4 a, const float* gp, float& m, float& s){
  const float4 g0 = *(const float4*)(gp);
  const float4 g1 = *(const float4*)(gp + 4);
  const float4 g2 = *(const float4*)(gp + 8);
  const float4 g3 = *(const float4*)(gp + 12);
  float t0  = __builtin_fmaf(cub0(a.x), ZS, g0.x);
  float t1  = __builtin_fmaf(cub1(a.x), ZS, g0.y);
  float t2  = __builtin_fmaf(cub2(a.x), ZS, g0.z);
  float t3  = __builtin_fmaf(cub3(a.x), ZS, g0.w);
  float t4  = __builtin_fmaf(cub0(a.y), ZS, g1.x);
  float t5  = __builtin_fmaf(cub1(a.y), ZS, g1.y);
  float t6  = __builtin_fmaf(cub2(a.y), ZS, g1.z);
  float t7  = __builtin_fmaf(cub3(a.y), ZS, g1.w);
  float t8  = __builtin_fmaf(cub0(a.z), ZS, g2.x);
  float t9  = __builtin_fmaf(cub1(a.z), ZS, g2.y);
  float t10 = __builtin_fmaf(cub2(a.z), ZS, g2.z);
  float t11 = __builtin_fmaf(cub3(a.z), ZS, g2.w);
  float t12 = __builtin_fmaf(cub0(a.w), ZS, g3.x);
  float t13 = __builtin_fmaf(cub1(a.w), ZS, g3.y);
  float t14 = __builtin_fmaf(cub2(a.w), ZS, g3.z);
  float t15 = __builtin_fmaf(cub3(a.w), ZS, g3.w);
  float a0 = fmaxf(t0, t1),   a1 = fmaxf(t2, t3);
  float a2 = fmaxf(t4, t5),   a3 = fmaxf(t6, t7);
  float a4 = fmaxf(t8, t9),   a5 = fmaxf(t10, t11);
  float a6 = fmaxf(t12, t13), a7 = fmaxf(t14, t15);
  float b0 = fmaxf(a0, a1), b1 = fmaxf(a2, a3), b2 = fmaxf(a4, a5), b3 = fmaxf(a6, a7);
  float nm = fmaxf(fmaxf(fmaxf(b0, b1), fmaxf(b2, b3)), m);
  float s0 = ex2(t0 - nm) + ex2(t1 - nm) + ex2(t2 - nm) + ex2(t3 - nm)
           + ex2(t4 - nm) + ex2(t5 - nm) + ex2(t6 - nm) + ex2(t7 - nm);
  float s1 = ex2(t8 - nm) + ex2(t9 - nm) + ex2(t10 - nm) + ex2(t11 - nm)
           + ex2(t12 - nm) + ex2(t13 - nm) + ex2(t14 - nm) + ex2(t15 - nm);
  s = __builtin_fmaf(s, ex2(m - nm), s0 + s1);
  m = nm;
}

// ---------------------------------------------------------------------------
// prep: row sum-of-squares + bf16 copies + init gts = -y2*LOG2E - BIAS (g0=0)
// ---------------------------------------------------------------------------
__global__ __launch_bounds__(256) void prep_k(const float* __restrict__ x, const float* __restrict__ y,
                                              u16* __restrict__ xb, u16* __restrict__ yb,
                                              float* __restrict__ x2, float* __restrict__ y2,
                                              float* __restrict__ gts){
  const int w = threadIdx.x >> 6, l = threadIdx.x & 63;
  const int r = blockIdx.x * 4 + w;         // 0..16383
  const bool isx = r < N;
  const int rr = isx ? r : r - N;
  const float* src = (isx ? x : y) + (size_t)rr * DK;
  float4 v = *(const float4*)(src + l * 4);
  ushort4 bv;
  bv.x = f2bf(v.x); bv.y = f2bf(v.y); bv.z = f2bf(v.z); bv.w = f2bf(v.w);
  *(ushort4*)((isx ? xb : yb) + (size_t)rr * DK + l * 4) = bv;
  float p = v.x*v.x + v.y*v.y + v.z*v.z + v.w*v.w;
  #pragma unroll
  for (int off = 32; off > 0; off >>= 1) p += __shfl_down(p, off);
  if (l == 0){
    if (isx) x2[rr] = p;
    else { y2[rr] = p; gts[rr] = -p * LOG2E - BIAS; }
  }
}

// ---------------------------------------------------------------------------
// gemm: z = xb*yb^T (bf16 MFMA). Quantize Zl = 2*log2e*z to biased uint8,
// stage tiles in LDS, store zq and zqT coalesced dwordx4.
// ---------------------------------------------------------------------------
__global__ __launch_bounds__(256) void gemm_k(const u16* __restrict__ xb, const u16* __restrict__ yb,
                                              unsigned char* __restrict__ zq,
                                              unsigned char* __restrict__ zqT){
  __shared__ __align__(16) u16 As[128 * 72];
  __shared__ __align__(16) u16 Bs[128 * 72];
  const int t = threadIdx.x;
  const int w = t >> 6, l = t & 63;
  const int wm = w >> 1, wn = w & 1;
  const int brow = blockIdx.y * 128, bcol = blockIdx.x * 128;
  const int tr = t >> 3, tc = t & 7;
  f32x4 acc[4][4] = {};
  for (int ks = 0; ks < 4; ++ks){
    #pragma unroll
    for (int rr = 0; rr < 4; ++rr){
      const int row = tr + rr * 32;
      *(ushort8*)&As[row * 72 + tc * 8] = *(const ushort8*)&xb[(size_t)(brow + row) * DK + ks * 64 + tc * 8];
      *(ushort8*)&Bs[row * 72 + tc * 8] = *(const ushort8*)&yb[(size_t)(bcol + row) * DK + ks * 64 + tc * 8];
    }
    __syncthreads();
    #pragma unroll
    for (int kk = 0; kk < 2; ++kk){
      bf16x8 av[4], bv[4];
      #pragma unroll
      for (int mi = 0; mi < 4; ++mi){
        const int ar = wm * 64 + mi * 16 + (l & 15);
        av[mi] = __builtin_bit_cast(bf16x8, *(const ushort8*)&As[ar * 72 + kk * 32 + (l >> 4) * 8]);
      }
      #pragma unroll
      for (int ni = 0; ni < 4; ++ni){
        const int br = wn * 64 + ni * 16 + (l & 15);
        bv[ni] = __builtin_bit_cast(bf16x8, *(const ushort8*)&Bs[br * 72 + kk * 32 + (l >> 4) * 8]);
      }
      #pragma unroll
      for (int mi = 0; mi < 4; ++mi)
        #pragma unroll
        for (int ni = 0; ni < 4; ++ni)
          acc[mi][ni] = __builtin_amdgcn_mfma_f32_16x16x32_bf16(av[mi], bv[ni], acc[mi][ni], 0, 0, 0);
    }
    __syncthreads();
  }
  // quantize: Cs row-major [128][128]; Ct col-major [col][row] stride 144
  unsigned char* Cs = (unsigned char*)As;
  unsigned char* Ct = (unsigned char*)Bs;
  #pragma unroll
  for (int mi = 0; mi < 4; ++mi){
    const int rowb = wm * 64 + mi * 16 + (l >> 4) * 4;
    #pragma unroll
    for (int ni = 0; ni < 4; ++ni){
      const int col = wn * 64 + ni * 16 + (l & 15);
      unsigned pk = 0;
      #pragma unroll
      for (int rr = 0; rr < 4; ++rr){
        float q = fminf(fmaxf(acc[mi][ni][rr] * QS, -127.f), 127.f);
        unsigned b = (unsigned)((int)__builtin_rintf(q) + 128) & 255u;
        Cs[(rowb + rr) * 128 + col] = (unsigned char)b;
        pk |= b << (8 * rr);
      }
      *(unsigned*)(Ct + col * 144 + rowb) = pk;
    }
  }
  __syncthreads();
  const int trow0 = t >> 3, kseg = t & 7;
  #pragma unroll
  for (int ii = 0; ii < 4; ++ii){
    const int row = trow0 + ii * 32;
    int4 v = *(const int4*)(Cs + row * 128 + kseg * 16);
    *(int4*)(zq + (size_t)(brow + row) * N + bcol + kseg * 16) = v;
    int4 vt = *(const int4*)(Ct + row * 144 + kseg * 16);
    *(int4*)(zqT + (size_t)(bcol + row) * N + brow + kseg * 16) = vt;
  }
}

// ---------------------------------------------------------------------------
// sweept: bootstrap dense sweep with full online-max tracking (1 row/wave).
// Also stores pmax_out[i] = lse2 for the premax kernels.
// ---------------------------------------------------------------------------
__global__ __launch_bounds__(256) void sweept_k(const unsigned char* __restrict__ z,
                                                const float* __restrict__ din,
                                                float* __restrict__ dout,
                                                float* __restrict__ pmax_out){
  const int w = threadIdx.x >> 6, l = threadIdx.x & 63;
  const int i = blockIdx.x * 4 + w;
  const unsigned char* zr = z + (size_t)i * N + l * 16;
  float m = -1e30f, s = 0.f;
  #pragma unroll 2
  for (int it = 0; it < 8; ++it){
    const uint4 zA = *(const uint4*)(zr + it * 1024);
    upd16(zA, din + it * 1024 + l * 16, m, s);
  }
  #pragma unroll
  for (int off = 32; off > 0; off >>= 1){
    float om = __shfl_down(m, off);
    float os = __shfl_down(s, off);
    float nm = fmaxf(m, om);
    s = __builtin_fmaf(s, ex2(m - nm), os * ex2(om - nm));
    m = nm;
  }
  if (l == 0){
    float lse2 = m + lg2(s);          // true lse2 (bias cancels)
    dout[i] = 13.0f - lse2 - BIAS;
    pmax_out[i] = lse2;
  }
}

// ---------------------------------------------------------------------------
// sweepf: premax dense sweep, 4 rows/wave full width, duals shared 4-ways.
// Grid 512 x 256 (4 waves/block, 16 rows/block). No LDS (avoids the 32-way
// bank conflict of the staged-dual variant; duals stream L1/L2 coalesced).
// s = sum 2^(t - M), M = row's previous-sweep lse (premax, exact math).
// MODE 0: dout[r] = 13 - lse - BIAS ; pmax_out[r] = lse
// MODE 1: r_i = 2^(fprev_true + lse - 26); contrib = (fprev_true*ln2 + x2)*r_i
// ---------------------------------------------------------------------------
template<int MODE>
__global__ __launch_bounds__(256) void sweepf_k(const unsigned char* __restrict__ z,
                                                const float* __restrict__ din,
                                                float* __restrict__ dout,
                                                const float* __restrict__ pmax_in,
                                                float* __restrict__ pmax_out,
                                                const float* __restrict__ fprev,
                                                const float* __restrict__ x2,
                                                float* __restrict__ contrib){
  const int w = threadIdx.x >> 6, l = threadIdx.x & 63;
  const int r0 = blockIdx.x * 16 + w * 4;
  const unsigned char* zr = z + (size_t)r0 * N + l * 16;
  const float M0 = pmax_in[r0],     M1 = pmax_in[r0 + 1];
  const float M2 = pmax_in[r0 + 2], M3 = pmax_in[r0 + 3];
  float s0 = 0.f, s1 = 0.f, s2 = 0.f, s3 = 0.f;
  #pragma unroll
  for (int it = 0; it < 8; ++it){
    const uint4 a0 = *(const uint4*)(zr + it * 1024);
    const uint4 a1 = *(const uint4*)(zr + N + it * 1024);
    const uint4 a2 = *(const uint4*)(zr + 2 * N + it * 1024);
    const uint4 a3 = *(const uint4*)(zr + 3 * N + it * 1024);
    const float* gp = din + it * 1024 + l * 16;
    const float4 g0 = *(const float4*)(gp);
    const float4 g1 = *(const float4*)(gp + 4);
    const float4 g2 = *(const float4*)(gp + 8);
    const float4 g3 = *(const float4*)(gp + 12);
    s0 += (quad(a0.x, g0, M0) + quad(a0.y, g1, M0))
        + (quad(a0.z, g2, M0) + quad(a0.w, g3, M0));
    s1 += (quad(a1.x, g0, M1) + quad(a1.y, g1, M1))
        + (quad(a1.z, g2, M1) + quad(a1.w, g3, M1));
    s2 += (quad(a2.x, g0, M2) + quad(a2.y, g1, M2))
        + (quad(a2.z, g2, M2) + quad(a2.w, g3, M2));
    s3 += (quad(a3.x, g0, M3) + quad(a3.y, g1, M3))
        + (quad(a3.z, g2, M3) + quad(a3.w, g3, M3));
  }
  #pragma unroll
  for (int off = 32; off > 0; off >>= 1){
    s0 += __shfl_down(s0, off);
    s1 += __shfl_down(s1, off);
    s2 += __shfl_down(s2, off);
    s3 += __shfl_down(s3, off);
  }
  if (l == 0){
    const float lse0 = M0 + lg2(s0);
    const float lse1 = M1 + lg2(s1);
    const float lse2 = M2 + lg2(s2);
    const float lse3 = M3 + lg2(s3);
    if (MODE == 0){
      dout[r0]     = 13.0f - lse0 - BIAS;
      dout[r0 + 1] = 13.0f - lse1 - BIAS;
      dout[r0 + 2] = 13.0f - lse2 - BIAS;
      dout[r0 + 3] = 13.0f - lse3 - BIAS;
      pmax_out[r0]     = lse0;
      pmax_out[r0 + 1] = lse1;
      pmax_out[r0 + 2] = lse2;
      pmax_out[r0 + 3] = lse3;
    } else {
      const float f0 = fprev[r0] + BIAS;        // true FtL
      const float f1 = fprev[r0 + 1] + BIAS;
      const float f2 = fprev[r0 + 2] + BIAS;
      const float f3 = fprev[r0 + 3] + BIAS;
      contrib[r0]     = (f0 * LN2 + x2[r0])     * ex2(f0 + lse0 - 26.0f);
      contrib[r0 + 1] = (f1 * LN2 + x2[r0 + 1]) * ex2(f1 + lse1 - 26.0f);
      contrib[r0 + 2] = (f2 * LN2 + x2[r0 + 2]) * ex2(f2 + lse2 - 26.0f);
      contrib[r0 + 3] = (f3 * LN2 + x2[r0 + 3]) * ex2(f3 + lse3 - 26.0f);
    }
  }
}

// ---------------------------------------------------------------------------
// finish: value = sum(contrib) + mean_j((gts_j+BIAS)*ln2 + y2_j); out = sqrt
// ---------------------------------------------------------------------------
__global__ __launch_bounds__(256) void finish_k(const float* __restrict__ contrib,
                                                const float* __restrict__ gts,
                                                const float* __restrict__ y2,
                                                float* __restrict__ out){
  __shared__ float s1[256], s2[256];
  const int t = threadIdx.x;
  float a = 0.f, b = 0.f;
  for (int j = t; j < N; j += 256){ a += contrib[j]; b += (gts[j] + BIAS) * LN2 + y2[j]; }
  s1[t] = a; s2[t] = b; __syncthreads();
  for (int st = 128; st > 0; st >>= 1){
    if (t < st){ s1[t] += s1[t + st]; s2[t] += s2[t + st]; }
    __syncthreads();
  }
  if (t == 0) out[0] = sqrtf(s1[0] + s2[0] * (1.0f / (float)N));
}

// ---------------------------------------------------------------------------
extern "C" void kernel_launch(void* const* d_in, const int* in_sizes, int n_in,
                              void* d_out, int out_size, void* d_ws, size_t ws_size,
                              hipStream_t stream){
  const float* x = (const float*)d_in[0];
  const float* y = (const float*)d_in[1];
  float* out = (float*)d_out;
  char* ws = (char*)d_ws;

  // workspace layout (bytes)
  unsigned char* zq  = (unsigned char*)(ws);              // 64 MiB
  unsigned char* zqT = (unsigned char*)(ws + 67108864);   // 64 MiB
  u16*   xb      = (u16*)  (ws + 134217728);              // 4 MiB
  u16*   yb      = (u16*)  (ws + 138412032);              // 4 MiB
  float* x2      = (float*)(ws + 142606336);
  float* y2      = (float*)(ws + 142639104);
  float* fts     = (float*)(ws + 142671872);
  float* gts     = (float*)(ws + 142704640);
  float* contrib = (float*)(ws + 142737408);
  float* pmaxF   = (float*)(ws + 142770176);
  float* pmaxG   = (float*)(ws + 142802944);

  prep_k<<<4096, 256, 0, stream>>>(x, y, xb, yb, x2, y2, gts);
  gemm_k<<<dim3(64, 64), 256, 0, stream>>>(xb, yb, zq, zqT);
  // bootstrap: 2 full iterations with online max (seeds pmax + duals)
  for (int it = 0; it < 2; ++it){
    sweept_k<<<2048, 256, 0, stream>>>(zq,  gts, fts, pmaxF);
    sweept_k<<<2048, 256, 0, stream>>>(zqT, fts, gts, pmaxG);
  }
  // premax sweeps, 4 rows/wave: s = 4..99 (even=f, odd=g)
  for (int s = 4; s < 100; ++s){
    if ((s & 1) == 0)
      sweepf_k<0><<<512, 256, 0, stream>>>(zq,  gts, fts, pmaxF, pmaxF,
                                           nullptr, nullptr, nullptr);
    else
      sweepf_k<0><<<512, 256, 0, stream>>>(zqT, fts, gts, pmaxG, pmaxG,
                                           nullptr, nullptr, nullptr);
  }
  // final value pass (f-side) + reduction
  sweepf_k<1><<<512, 256, 0, stream>>>(zq, gts, nullptr, pmaxF, nullptr,
                                       fts, x2, contrib);
  finish_k<<<1, 256, 0, stream>>>(contrib, gts, y2, out);
}